// Round 1
// baseline (766.969 us; speedup 1.0000x reference)
//
#include <hip/hip_runtime.h>
#include <math.h>

#define FIN 128
#define FOUT 64
#define MAXDEG 64

// ---------------- helpers ----------------

__device__ __forceinline__ float wave_sum(float v) {
#pragma unroll
  for (int off = 32; off >= 1; off >>= 1) v += __shfl_xor(v, off, 64);
  return v;
}

// logmap0 row factor: artanh(clip(n))/max(n,1e-15), c=1
__device__ __forceinline__ float row_scale(float ss) {
  float n  = sqrtf(ss);
  float nc = fmaxf(n, 1e-15f);
  float t  = fminf(nc, 1.0f - 1e-7f);
  float at = 0.5f * (log1pf(t) - log1pf(-t));
  return at / nc;
}

// ---------------- kernel 1: logmap0 + GEMM(128->64) + leaky_relu ----------------
// One wave processes 4 nodes; lane = output feature. W^T staged in LDS padded
// (stride 132 words -> b128 reads land 8 words/bank, balanced). x rows read as
// all-lane-uniform float4 broadcasts from global (L1-resident, 2KB/group).
__global__ __launch_bounds__(256) void k_gemm(const float* __restrict__ x,
                                              const float* __restrict__ Wup,
                                              float* __restrict__ u,
                                              int ngroups) {
  __shared__ float Wt[64 * 132];
  int tid = threadIdx.x;
  for (int idx = tid; idx < FIN * FOUT; idx += 256) {
    int k = idx >> 6, f = idx & 63;
    Wt[f * 132 + k] = Wup[idx];   // Wup[k][f] row-major
  }
  __syncthreads();
  int lane = tid & 63, wv = tid >> 6;
  for (int g = blockIdx.x * 4 + wv; g < ngroups; g += gridDim.x * 4) {
    const float* xg = x + (size_t)g * 512;  // 4 nodes x 128
    float4 a0 = ((const float4*)xg)[lane];        // words [0,256)  -> nodes 0,1
    float4 a1 = ((const float4*)xg)[64 + lane];   // words [256,512)-> nodes 2,3
    float p1 = a0.x*a0.x + a0.y*a0.y + a0.z*a0.z + a0.w*a0.w;
    float p2 = a1.x*a1.x + a1.y*a1.y + a1.z*a1.z + a1.w*a1.w;
#pragma unroll
    for (int off = 1; off <= 16; off <<= 1) {   // reduce within 32-lane halves
      p1 += __shfl_xor(p1, off, 64);
      p2 += __shfl_xor(p2, off, 64);
    }
    float sc0 = row_scale(__shfl(p1, 0, 64));
    float sc1 = row_scale(__shfl(p1, 32, 64));
    float sc2 = row_scale(__shfl(p2, 0, 64));
    float sc3 = row_scale(__shfl(p2, 32, 64));

    float acc0 = 0.f, acc1 = 0.f, acc2 = 0.f, acc3 = 0.f;
    const float4* x0 = (const float4*)(xg);
    const float4* x1 = (const float4*)(xg + 128);
    const float4* x2 = (const float4*)(xg + 256);
    const float4* x3 = (const float4*)(xg + 384);
    const float* wrow = &Wt[lane * 132];
#pragma unroll 8
    for (int kk = 0; kk < 32; ++kk) {
      float4 w4 = *(const float4*)(wrow + kk * 4);
      float4 b0 = x0[kk], b1 = x1[kk], b2 = x2[kk], b3 = x3[kk];
      acc0 = fmaf(b0.x, w4.x, acc0); acc0 = fmaf(b0.y, w4.y, acc0);
      acc0 = fmaf(b0.z, w4.z, acc0); acc0 = fmaf(b0.w, w4.w, acc0);
      acc1 = fmaf(b1.x, w4.x, acc1); acc1 = fmaf(b1.y, w4.y, acc1);
      acc1 = fmaf(b1.z, w4.z, acc1); acc1 = fmaf(b1.w, w4.w, acc1);
      acc2 = fmaf(b2.x, w4.x, acc2); acc2 = fmaf(b2.y, w4.y, acc2);
      acc2 = fmaf(b2.z, w4.z, acc2); acc2 = fmaf(b2.w, w4.w, acc2);
      acc3 = fmaf(b3.x, w4.x, acc3); acc3 = fmaf(b3.y, w4.y, acc3);
      acc3 = fmaf(b3.z, w4.z, acc3); acc3 = fmaf(b3.w, w4.w, acc3);
    }
    float v0 = sc0 * acc0, v1 = sc1 * acc1, v2 = sc2 * acc2, v3 = sc3 * acc3;
    v0 = (v0 >= 0.f) ? v0 : 0.01f * v0;
    v1 = (v1 >= 0.f) ? v1 : 0.01f * v1;
    v2 = (v2 >= 0.f) ? v2 : 0.01f * v2;
    v3 = (v3 >= 0.f) ? v3 : 0.01f * v3;
    size_t base = (size_t)g * 4 * 64 + lane;
    u[base]       = v0;
    u[base + 64]  = v1;
    u[base + 128] = v2;
    u[base + 192] = v3;
  }
}

// ---------------- kernel 2: padded-CSR fill ----------------
__global__ __launch_bounds__(256) void k_fill(const int* __restrict__ ei, int E,
                                              int* __restrict__ deg,
                                              int* __restrict__ slots) {
  int e = blockIdx.x * 256 + threadIdx.x;
  if (e >= E) return;
  int s = ei[e];
  int d = ei[E + e];
  int pos = atomicAdd(&deg[d], 1);
  if (pos < MAXDEG) slots[d * MAXDEG + pos] = s;
}

// ---------------- kernel 3: agg1 (sum_neigh) + softmax gate ----------------
__global__ __launch_bounds__(256) void k_agg1(const int* __restrict__ deg,
                                              const int* __restrict__ slots,
                                              const float* __restrict__ u,
                                              const float* __restrict__ Wpl,
                                              float* __restrict__ sumn,
                                              float* __restrict__ selF, int N) {
  int wv = threadIdx.x >> 6, lane = threadIdx.x & 63;
  int i = blockIdx.x * 4 + wv;
  if (i >= N) return;
  int d = min(deg[i], MAXDEG);
  const int* sl = slots + i * MAXDEG;
  float acc = 0.f;
  for (int e = 0; e < d; ++e) {
    int s = sl[e];                       // wave-uniform
    acc += u[(size_t)s * 64 + lane];     // 256B coalesced gather
  }
  sumn[(size_t)i * 64 + lane] = acc;
  float l0 = wave_sum(acc * Wpl[lane * 2]);
  float l1 = wave_sum(acc * Wpl[lane * 2 + 1]);
  float r0 = fmaxf(l0, 0.f), r1 = fmaxf(l1, 0.f);
  float m  = fmaxf(r0, r1);
  float e0 = expf(r0 - m), e1 = expf(r1 - m);
  float p1 = e1 / (e0 + e1);
  if (lane == 0) selF[i] = (p1 > 0.48f) ? 1.f : 0.f;
}

// ---------------- kernel 4: agg2 (sum_sel, register-only) + weight_sel ----------------
__global__ __launch_bounds__(256) void k_agg2(const int* __restrict__ deg,
                                              const int* __restrict__ slots,
                                              const float* __restrict__ u,
                                              const float* __restrict__ Wlw,
                                              const float* __restrict__ sumn,
                                              const float* __restrict__ selF,
                                              float* __restrict__ cF, int N) {
  int wv = threadIdx.x >> 6, lane = threadIdx.x & 63;
  int i = blockIdx.x * 4 + wv;
  if (i >= N) return;
  int d = min(deg[i], MAXDEG);
  const int* sl = slots + i * MAXDEG;
  float acc = 0.f;
  for (int e = 0; e < d; ++e) {
    int s = sl[e];
    if (selF[s] != 0.f) acc += u[(size_t)s * 64 + lane];  // uniform branch skips row
  }
  float sn = sumn[(size_t)i * 64 + lane];
  float t  = wave_sum(acc * Wlw[lane] + sn * Wlw[64 + lane]);
  float sig = 1.f / (1.f + expf(-t));
  if (lane == 0) cF[i] = (selF[i] != 0.f) ? sig : 0.f;   // wsel*sel
}

// ---------------- kernel 5: agg3 + relu + add + expmap0 + proj ----------------
__global__ __launch_bounds__(256) void k_agg3(const int* __restrict__ deg,
                                              const int* __restrict__ slots,
                                              const float* __restrict__ u,
                                              const float* __restrict__ cF,
                                              float* __restrict__ out, int N) {
  int wv = threadIdx.x >> 6, lane = threadIdx.x & 63;
  int i = blockIdx.x * 4 + wv;
  if (i >= N) return;
  int d = min(deg[i], MAXDEG);
  const int* sl = slots + i * MAXDEG;
  float acc = 0.f;
  for (int e = 0; e < d; ++e) {
    int s = sl[e];
    float cv = cF[s];
    if (cv != 0.f) acc = fmaf(cv, u[(size_t)s * 64 + lane], acc);
  }
  float ov = u[(size_t)i * 64 + lane] + fmaxf(acc, 0.f);  // relu(a_x) + u
  // expmap0
  float ss = wave_sum(ov * ov);
  float nc = fmaxf(sqrtf(ss), 1e-15f);
  float fac = tanhf(nc) / nc;
  float r = ov * fac;
  // proj (recompute norm like the reference does)
  float ss2 = wave_sum(r * r);
  float n2 = fmaxf(sqrtf(ss2), 1e-15f);
  float maxn = 1.0f - 4e-3f;
  float res = (n2 > maxn) ? r * (maxn / n2) : r;
  out[(size_t)i * 64 + lane] = res;
}

// ---------------- launch ----------------
extern "C" void kernel_launch(void* const* d_in, const int* in_sizes, int n_in,
                              void* d_out, int out_size, void* d_ws, size_t ws_size,
                              hipStream_t stream) {
  const float* x   = (const float*)d_in[0];
  const int*   ei  = (const int*)d_in[1];
  const float* Wup = (const float*)d_in[2];
  const float* Wpl = (const float*)d_in[3];
  const float* Wlw = (const float*)d_in[4];
  float* out = (float*)d_out;

  int N = in_sizes[0] / FIN;     // 100000
  int E = in_sizes[1] / 2;       // 1600000

  char* ws = (char*)d_ws;
  float* u    = (float*)ws;                          // N*64 f32 = 25.6 MB
  float* sumn = u + (size_t)N * 64;                  // 25.6 MB
  int*   slots = (int*)(sumn + (size_t)N * 64);      // N*64 i32 = 25.6 MB
  int*   deg   = slots + (size_t)N * MAXDEG;         // 0.4 MB
  float* selF  = (float*)(deg + N);                  // 0.4 MB
  float* cF    = selF + N;                           // 0.4 MB  (total ~78 MB)

  hipMemsetAsync(deg, 0, (size_t)N * sizeof(int), stream);

  int ngroups = (N + 3) / 4;
  k_gemm<<<2048, 256, 0, stream>>>(x, Wup, u, ngroups);
  k_fill<<<(E + 255) / 256, 256, 0, stream>>>(ei, E, deg, slots);
  int nblk = (N + 3) / 4;
  k_agg1<<<nblk, 256, 0, stream>>>(deg, slots, u, Wpl, sumn, selF, N);
  k_agg2<<<nblk, 256, 0, stream>>>(deg, slots, u, Wlw, sumn, selF, cF, N);
  k_agg3<<<nblk, 256, 0, stream>>>(deg, slots, u, cF, out, N);
}

// Round 2
// 495.777 us; speedup vs baseline: 1.5470x; 1.5470x over previous
//
#include <hip/hip_runtime.h>
#include <math.h>

#define FIN 128
#define FOUT 64
#define MAXDEG 64

// ---------------- helpers ----------------

__device__ __forceinline__ float4 f4add(float4 a, float4 b) {
  return make_float4(a.x + b.x, a.y + b.y, a.z + b.z, a.w + b.w);
}
__device__ __forceinline__ float4 f4fma(float c, float4 v, float4 a) {
  return make_float4(fmaf(c, v.x, a.x), fmaf(c, v.y, a.y),
                     fmaf(c, v.z, a.z), fmaf(c, v.w, a.w));
}
__device__ __forceinline__ float4 f4shflxor(float4 v, int off) {
  return make_float4(__shfl_xor(v.x, off, 64), __shfl_xor(v.y, off, 64),
                     __shfl_xor(v.z, off, 64), __shfl_xor(v.w, off, 64));
}
// reduce across the 16 lanes of each quarter-wave (values replicated per group)
__device__ __forceinline__ float red16(float v) {
  v += __shfl_xor(v, 1, 64);
  v += __shfl_xor(v, 2, 64);
  v += __shfl_xor(v, 4, 64);
  v += __shfl_xor(v, 8, 64);
  return v;
}

// logmap0 row factor: artanh(clip(n))/max(n,1e-15), c=1
__device__ __forceinline__ float row_scale(float ss) {
  float n  = sqrtf(ss);
  float nc = fmaxf(n, 1e-15f);
  float t  = fminf(nc, 1.0f - 1e-7f);
  float at = 0.5f * (log1pf(t) - log1pf(-t));
  return at / nc;
}

// ---------------- kernel 1: logmap0 + GEMM(128->64) + leaky_relu ----------------
__global__ __launch_bounds__(256) void k_gemm(const float* __restrict__ x,
                                              const float* __restrict__ Wup,
                                              float* __restrict__ u,
                                              int ngroups) {
  __shared__ float Wt[64 * 132];
  int tid = threadIdx.x;
  for (int idx = tid; idx < FIN * FOUT; idx += 256) {
    int k = idx >> 6, f = idx & 63;
    Wt[f * 132 + k] = Wup[idx];   // Wup[k][f] row-major
  }
  __syncthreads();
  int lane = tid & 63, wv = tid >> 6;
  for (int g = blockIdx.x * 4 + wv; g < ngroups; g += gridDim.x * 4) {
    const float* xg = x + (size_t)g * 512;  // 4 nodes x 128
    float4 a0 = ((const float4*)xg)[lane];
    float4 a1 = ((const float4*)xg)[64 + lane];
    float p1 = a0.x*a0.x + a0.y*a0.y + a0.z*a0.z + a0.w*a0.w;
    float p2 = a1.x*a1.x + a1.y*a1.y + a1.z*a1.z + a1.w*a1.w;
#pragma unroll
    for (int off = 1; off <= 16; off <<= 1) {
      p1 += __shfl_xor(p1, off, 64);
      p2 += __shfl_xor(p2, off, 64);
    }
    float sc0 = row_scale(__shfl(p1, 0, 64));
    float sc1 = row_scale(__shfl(p1, 32, 64));
    float sc2 = row_scale(__shfl(p2, 0, 64));
    float sc3 = row_scale(__shfl(p2, 32, 64));

    float acc0 = 0.f, acc1 = 0.f, acc2 = 0.f, acc3 = 0.f;
    const float4* x0 = (const float4*)(xg);
    const float4* x1 = (const float4*)(xg + 128);
    const float4* x2 = (const float4*)(xg + 256);
    const float4* x3 = (const float4*)(xg + 384);
    const float* wrow = &Wt[lane * 132];
#pragma unroll 8
    for (int kk = 0; kk < 32; ++kk) {
      float4 w4 = *(const float4*)(wrow + kk * 4);
      float4 b0 = x0[kk], b1 = x1[kk], b2 = x2[kk], b3 = x3[kk];
      acc0 = fmaf(b0.x, w4.x, acc0); acc0 = fmaf(b0.y, w4.y, acc0);
      acc0 = fmaf(b0.z, w4.z, acc0); acc0 = fmaf(b0.w, w4.w, acc0);
      acc1 = fmaf(b1.x, w4.x, acc1); acc1 = fmaf(b1.y, w4.y, acc1);
      acc1 = fmaf(b1.z, w4.z, acc1); acc1 = fmaf(b1.w, w4.w, acc1);
      acc2 = fmaf(b2.x, w4.x, acc2); acc2 = fmaf(b2.y, w4.y, acc2);
      acc2 = fmaf(b2.z, w4.z, acc2); acc2 = fmaf(b2.w, w4.w, acc2);
      acc3 = fmaf(b3.x, w4.x, acc3); acc3 = fmaf(b3.y, w4.y, acc3);
      acc3 = fmaf(b3.z, w4.z, acc3); acc3 = fmaf(b3.w, w4.w, acc3);
    }
    float v0 = sc0 * acc0, v1 = sc1 * acc1, v2 = sc2 * acc2, v3 = sc3 * acc3;
    v0 = (v0 >= 0.f) ? v0 : 0.01f * v0;
    v1 = (v1 >= 0.f) ? v1 : 0.01f * v1;
    v2 = (v2 >= 0.f) ? v2 : 0.01f * v2;
    v3 = (v3 >= 0.f) ? v3 : 0.01f * v3;
    size_t base = (size_t)g * 4 * 64 + lane;
    u[base]       = v0;
    u[base + 64]  = v1;
    u[base + 128] = v2;
    u[base + 192] = v3;
  }
}

// ---------------- kernel 2: padded-CSR fill ----------------
__global__ __launch_bounds__(256) void k_fill(const int* __restrict__ ei, int E,
                                              int* __restrict__ deg,
                                              int* __restrict__ slots) {
  int e = blockIdx.x * 256 + threadIdx.x;
  if (e >= E) return;
  int s = ei[e];
  int d = ei[E + e];
  int pos = atomicAdd(&deg[d], 1);
  if (pos < MAXDEG) slots[d * MAXDEG + pos] = s;
}

// ---------------- agg kernels: 4 edges in parallel per wave ----------------
// lane = 16*sub + l4.  Group `sub` handles edges e+4*sub+{0..3}; each lane
// loads a float4 (16 lanes x 16B = one full 256B u-row). Up to 16 row-gathers
// in flight per wave. Cross-group reduce: shfl_xor 16,32.

__global__ __launch_bounds__(256) void k_agg1(const int* __restrict__ deg,
                                              const int* __restrict__ slots,
                                              const float* __restrict__ u,
                                              const float* __restrict__ Wpl,
                                              float* __restrict__ sumn,
                                              float* __restrict__ selF, int N) {
  int wv = threadIdx.x >> 6, lane = threadIdx.x & 63;
  int i = blockIdx.x * 4 + wv;
  if (i >= N) return;
  int d = min(deg[i], MAXDEG);
  const int* sl = slots + (size_t)i * MAXDEG;
  int sub = lane >> 4, l4 = lane & 15;
  float4 acc0 = make_float4(0, 0, 0, 0), acc1 = make_float4(0, 0, 0, 0);
  for (int e = 0; e < d; e += 16) {
    int4 sv = ((const int4*)(sl + e))[sub];   // 16B broadcast per group
    int base = e + sub * 4;
    float4 v0 = make_float4(0,0,0,0), v1 = v0, v2 = v0, v3 = v0;
    if (base < d)     v0 = ((const float4*)(u + (size_t)sv.x * 64))[l4];
    if (base + 1 < d) v1 = ((const float4*)(u + (size_t)sv.y * 64))[l4];
    if (base + 2 < d) v2 = ((const float4*)(u + (size_t)sv.z * 64))[l4];
    if (base + 3 < d) v3 = ((const float4*)(u + (size_t)sv.w * 64))[l4];
    acc0 = f4add(acc0, f4add(v0, v1));
    acc1 = f4add(acc1, f4add(v2, v3));
  }
  float4 acc = f4add(acc0, acc1);
  acc = f4add(acc, f4shflxor(acc, 16));
  acc = f4add(acc, f4shflxor(acc, 32));   // replicated across groups
  if (sub == 0) ((float4*)(sumn + (size_t)i * 64))[l4] = acc;
  int f = l4 * 4;
  float l0 = acc.x * Wpl[f * 2]       + acc.y * Wpl[(f + 1) * 2]
           + acc.z * Wpl[(f + 2) * 2] + acc.w * Wpl[(f + 3) * 2];
  float l1 = acc.x * Wpl[f * 2 + 1]       + acc.y * Wpl[(f + 1) * 2 + 1]
           + acc.z * Wpl[(f + 2) * 2 + 1] + acc.w * Wpl[(f + 3) * 2 + 1];
  l0 = red16(l0); l1 = red16(l1);
  float r0 = fmaxf(l0, 0.f), r1 = fmaxf(l1, 0.f);
  float m  = fmaxf(r0, r1);
  float e0 = expf(r0 - m), e1 = expf(r1 - m);
  float p1 = e1 / (e0 + e1);
  if (lane == 0) selF[i] = (p1 > 0.48f) ? 1.f : 0.f;
}

__global__ __launch_bounds__(256) void k_agg2(const int* __restrict__ deg,
                                              const int* __restrict__ slots,
                                              const float* __restrict__ u,
                                              const float* __restrict__ Wlw,
                                              const float* __restrict__ sumn,
                                              const float* __restrict__ selF,
                                              float* __restrict__ cF, int N) {
  int wv = threadIdx.x >> 6, lane = threadIdx.x & 63;
  int i = blockIdx.x * 4 + wv;
  if (i >= N) return;
  int d = min(deg[i], MAXDEG);
  const int* sl = slots + (size_t)i * MAXDEG;
  int sub = lane >> 4, l4 = lane & 15;
  float4 acc0 = make_float4(0, 0, 0, 0), acc1 = make_float4(0, 0, 0, 0);
  for (int e = 0; e < d; e += 16) {
    int4 sv = ((const int4*)(sl + e))[sub];
    int base = e + sub * 4;
    float g0 = 0.f, g1 = 0.f, g2 = 0.f, g3 = 0.f;
    if (base < d)     g0 = selF[sv.x];
    if (base + 1 < d) g1 = selF[sv.y];
    if (base + 2 < d) g2 = selF[sv.z];
    if (base + 3 < d) g3 = selF[sv.w];
    float4 v0 = make_float4(0,0,0,0), v1 = v0, v2 = v0, v3 = v0;
    if (g0 != 0.f) v0 = ((const float4*)(u + (size_t)sv.x * 64))[l4];
    if (g1 != 0.f) v1 = ((const float4*)(u + (size_t)sv.y * 64))[l4];
    if (g2 != 0.f) v2 = ((const float4*)(u + (size_t)sv.z * 64))[l4];
    if (g3 != 0.f) v3 = ((const float4*)(u + (size_t)sv.w * 64))[l4];
    acc0 = f4add(acc0, f4add(v0, v1));
    acc1 = f4add(acc1, f4add(v2, v3));
  }
  float4 acc = f4add(acc0, acc1);
  acc = f4add(acc, f4shflxor(acc, 16));
  acc = f4add(acc, f4shflxor(acc, 32));
  float4 sn = ((const float4*)(sumn + (size_t)i * 64))[l4];
  int f = l4 * 4;
  float t = acc.x * Wlw[f]     + acc.y * Wlw[f + 1]
          + acc.z * Wlw[f + 2] + acc.w * Wlw[f + 3]
          + sn.x * Wlw[64 + f]     + sn.y * Wlw[64 + f + 1]
          + sn.z * Wlw[64 + f + 2] + sn.w * Wlw[64 + f + 3];
  t = red16(t);
  float sig = 1.f / (1.f + expf(-t));
  if (lane == 0) cF[i] = (selF[i] != 0.f) ? sig : 0.f;
}

__global__ __launch_bounds__(256) void k_agg3(const int* __restrict__ deg,
                                              const int* __restrict__ slots,
                                              const float* __restrict__ u,
                                              const float* __restrict__ cF,
                                              float* __restrict__ out, int N) {
  int wv = threadIdx.x >> 6, lane = threadIdx.x & 63;
  int i = blockIdx.x * 4 + wv;
  if (i >= N) return;
  int d = min(deg[i], MAXDEG);
  const int* sl = slots + (size_t)i * MAXDEG;
  int sub = lane >> 4, l4 = lane & 15;
  float4 acc0 = make_float4(0, 0, 0, 0), acc1 = make_float4(0, 0, 0, 0);
  for (int e = 0; e < d; e += 16) {
    int4 sv = ((const int4*)(sl + e))[sub];
    int base = e + sub * 4;
    float c0 = 0.f, c1 = 0.f, c2 = 0.f, c3 = 0.f;
    if (base < d)     c0 = cF[sv.x];
    if (base + 1 < d) c1 = cF[sv.y];
    if (base + 2 < d) c2 = cF[sv.z];
    if (base + 3 < d) c3 = cF[sv.w];
    float4 v0 = make_float4(0,0,0,0), v1 = v0, v2 = v0, v3 = v0;
    if (c0 != 0.f) v0 = ((const float4*)(u + (size_t)sv.x * 64))[l4];
    if (c1 != 0.f) v1 = ((const float4*)(u + (size_t)sv.y * 64))[l4];
    if (c2 != 0.f) v2 = ((const float4*)(u + (size_t)sv.z * 64))[l4];
    if (c3 != 0.f) v3 = ((const float4*)(u + (size_t)sv.w * 64))[l4];
    acc0 = f4fma(c0, v0, acc0);
    acc0 = f4fma(c1, v1, acc0);
    acc1 = f4fma(c2, v2, acc1);
    acc1 = f4fma(c3, v3, acc1);
  }
  float4 acc = f4add(acc0, acc1);
  acc = f4add(acc, f4shflxor(acc, 16));
  acc = f4add(acc, f4shflxor(acc, 32));
  float4 uv = ((const float4*)(u + (size_t)i * 64))[l4];
  float4 ov = make_float4(uv.x + fmaxf(acc.x, 0.f), uv.y + fmaxf(acc.y, 0.f),
                          uv.z + fmaxf(acc.z, 0.f), uv.w + fmaxf(acc.w, 0.f));
  float ssp = ov.x * ov.x + ov.y * ov.y + ov.z * ov.z + ov.w * ov.w;
  float ss  = red16(ssp);
  float nc  = fmaxf(sqrtf(ss), 1e-15f);
  float th  = tanhf(nc);
  float fac = th / nc;
  float4 r = make_float4(ov.x * fac, ov.y * fac, ov.z * fac, ov.w * fac);
  float n2 = fmaxf(th, 1e-15f);   // |r| = tanh(nc) exactly (up to f32 rounding)
  float maxn = 1.0f - 4e-3f;
  float s = (n2 > maxn) ? (maxn / n2) : 1.0f;
  float4 res = make_float4(r.x * s, r.y * s, r.z * s, r.w * s);
  if (sub == 0) ((float4*)(out + (size_t)i * 64))[l4] = res;
}

// ---------------- launch ----------------
extern "C" void kernel_launch(void* const* d_in, const int* in_sizes, int n_in,
                              void* d_out, int out_size, void* d_ws, size_t ws_size,
                              hipStream_t stream) {
  const float* x   = (const float*)d_in[0];
  const int*   ei  = (const int*)d_in[1];
  const float* Wup = (const float*)d_in[2];
  const float* Wpl = (const float*)d_in[3];
  const float* Wlw = (const float*)d_in[4];
  float* out = (float*)d_out;

  int N = in_sizes[0] / FIN;     // 100000
  int E = in_sizes[1] / 2;       // 1600000

  char* ws = (char*)d_ws;
  float* u    = (float*)ws;                          // N*64 f32 = 25.6 MB
  float* sumn = u + (size_t)N * 64;                  // 25.6 MB
  int*   slots = (int*)(sumn + (size_t)N * 64);      // N*64 i32 = 25.6 MB
  int*   deg   = slots + (size_t)N * MAXDEG;         // 0.4 MB
  float* selF  = (float*)(deg + N);                  // 0.4 MB
  float* cF    = selF + N;                           // 0.4 MB

  hipMemsetAsync(deg, 0, (size_t)N * sizeof(int), stream);

  int ngroups = (N + 3) / 4;
  k_gemm<<<2048, 256, 0, stream>>>(x, Wup, u, ngroups);
  k_fill<<<(E + 255) / 256, 256, 0, stream>>>(ei, E, deg, slots);
  int nblk = (N + 3) / 4;
  k_agg1<<<nblk, 256, 0, stream>>>(deg, slots, u, Wpl, sumn, selF, N);
  k_agg2<<<nblk, 256, 0, stream>>>(deg, slots, u, Wlw, sumn, selF, cF, N);
  k_agg3<<<nblk, 256, 0, stream>>>(deg, slots, u, cF, out, N);
}